// Round 8
// baseline (206.984 us; speedup 1.0000x reference)
//
#include <hip/hip_runtime.h>
#include <stdint.h>

#define IN_DIM 4096
#define H_DIM  2048
#define NPTS   2097152

typedef short  bf16x8  __attribute__((ext_vector_type(8)));
typedef float  floatx4 __attribute__((ext_vector_type(4)));

#define AS1 __attribute__((address_space(1)))
#define AS3 __attribute__((address_space(3)))

__device__ __forceinline__ unsigned short f2bf(float f) {
    unsigned u = __float_as_uint(f);
    unsigned r = (u + 0x7FFFu + ((u >> 16) & 1u)) >> 16;   // RNE
    return (unsigned short)r;
}

// Fast tanh: tanh(x) = 1 - 2/(exp(2x)+1) via v_exp_f32 + v_rcp_f32.
__device__ __forceinline__ float tanh_fast(float x) {
    float e = __builtin_amdgcn_exp2f(x * 2.885390081777927f);   // exp(2x)
    return 1.0f - 2.0f * __builtin_amdgcn_rcpf(e + 1.0f);
}

// ---------------- Kernel 1: prep_h + prep_w2t merged; also zeros rowsum ----------------
__global__ void prep_all(const float* __restrict__ W1, const float* __restrict__ b1,
                         const float* __restrict__ W2,
                         unsigned short* __restrict__ hbf, unsigned short* __restrict__ W2T,
                         float* __restrict__ rowsum) {
    __shared__ unsigned short tile[64][66];
    int b = blockIdx.x;
    if (b < 8192) {
        if (b < 16) rowsum[b * 256 + threadIdx.x] = 0.0f;   // 16*256 = 4096
        int idx = (b * 256 + threadIdx.x) * 4;              // covers 8388608
        float4 w = *(const float4*)(W1 + idx);
        float4 bb = *(const float4*)(b1 + (idx & (H_DIM - 1)));
        ushort4 o;
        o.x = f2bf(tanh_fast(w.x + bb.x));
        o.y = f2bf(tanh_fast(w.y + bb.y));
        o.z = f2bf(tanh_fast(w.z + bb.z));
        o.w = f2bf(tanh_fast(w.w + bb.w));
        *(ushort4*)(hbf + idx) = o;
    } else {
        int bb = b - 8192;
        int k0 = (bb >> 5) * 64, n0 = (bb & 31) * 64;
        for (int idx = threadIdx.x; idx < 64 * 64; idx += 256) {
            int r = idx >> 6, c = idx & 63;             // c fast -> coalesced read of W2 row
            tile[c][r] = f2bf(W2[(size_t)(k0 + r) * H_DIM + n0 + c]);
        }
        __syncthreads();
        for (int idx = threadIdx.x; idx < 64 * 64; idx += 256) {
            int r = idx >> 6, c = idx & 63;             // c fast -> coalesced write of W2T row
            W2T[(size_t)(n0 + r) * H_DIM + k0 + c] = tile[r][c];
        }
    }
}

// ---------------- Kernel 2: fused GEMM + tanh + @W3 row-reduce ----------------
// R6 accounting: 18 LDS ops/wave-tile (12 ds_read + 6 staging writes) ~= 216
// LDS-pipe cyc vs 78 MFMA cyc -> LDS-throughput-bound. Lever: B never touches
// LDS (lane(lane16,quad,ni) needs BT[col][k0+s*32+quad*8..+8] = one contiguous
// 16 B global load from the XCD-local L2 panel). LDS ops drop to 12/wave-tile.
// R7 FAILED (NaN): counted vmcnt(4) assumed [4 gload_lds][4 B-loads] issue
// order; scheduler interleaved them -> vmcnt(4) left a gload_lds in flight ->
// COMPUTE read unstaged LDS (rule-#18 class: counted waits need pinned order).
// R8: counting-free schedule. Keep R0's proven vmcnt(0)-drain structure and
// issue the B-prefetch AFTER the drain barrier:
//   TOPSYNC(lgkm0+bar); STAGEA(k); VMSYNC(vm0+bar); LOADB(next); COMPUTE(cur)
// LOADB(next) overlaps COMPUTE+TOPSYNC+STAGEA (>=400 cy) and is drained at the
// NEXT region's vmcnt(0) -> hidden, and ANY in-region reordering is harmless
// (everything outstanding drains at the next vmcnt(0); memory clobbers pin
// loads inside their region). Only exposed latency = STAGEA drain, same as
// R0-R6. LDS 24 KB -> 16 KB. A staging + fragment swizzle unchanged (0 conf).
// XCD-region swizzle (R5 WIN: FETCH 69.8->33 MB) kept.
#define BK 64
__global__ __launch_bounds__(256, 4) void gemm_fused(
    const unsigned short* __restrict__ A,    // 4096 x 2048 bf16 (h)
    const unsigned short* __restrict__ BT,   // 2048 x 2048 bf16 (W2^T, N x K)
    const float* __restrict__ b2, const float* __restrict__ W3,
    float* __restrict__ rowsum) {
    __shared__ __align__(16) unsigned short As[128 * BK];   // 16 KB (A only)
    const int K = H_DIM;
    const int t = threadIdx.x;
    const int w = t >> 6, l = t & 63;
    const int lane16 = l & 15, quad = l >> 4;
    const int wr = w >> 1, wc = w & 1;                      // 2x2 waves over 128x64

    // XCD-region swizzle (8 by x 16 bx per XCD)
    const int bid = blockIdx.x;
    const int xcd = bid & 7, idx = bid >> 3;
    const int by = (xcd >> 1) * 8 + (idx >> 4);
    const int bx = (xcd & 1) * 16 + (idx & 15);
    const int rowBase = by * 128;
    const int colBase = bx * 64;

    // per-lane A staging offset within an 8-row group (elements)
    const int sRow = l >> 3;                   // 0..7
    const int sChunk = (l & 7) ^ sRow;         // swizzled data chunk
    const size_t laneOff = (size_t)sRow * K + sChunk * 8;
    const unsigned short* aBase = A + (size_t)(rowBase + w * 32) * K + laneOff;

    // per-lane B direct-load base: row = output col, contiguous 16B in K
    const unsigned short* bDir =
        BT + (size_t)(colBase + wc * 32 + lane16) * K + quad * 8;

    floatx4 acc[4][2];
    floatx4 zero = {0.f, 0.f, 0.f, 0.f};
#pragma unroll
    for (int i = 0; i < 4; ++i)
#pragma unroll
        for (int j = 0; j < 2; ++j) acc[i][j] = zero;

    bf16x8 bA[2][2], bB[2][2];   // [s][ni], all indices compile-time (rule #20)

#define STAGEA(k0)                                                             \
    {                                                                          \
        _Pragma("unroll")                                                      \
        for (int i = 0; i < 4; ++i)                                            \
            __builtin_amdgcn_global_load_lds(                                  \
                (const AS1 void*)(aBase + (size_t)i * 8 * K + (k0)),           \
                (AS3 void*)(As + (w * 32 + i * 8) * 64), 16, 0, 0);            \
    }

#define LOADB(dst, k0)                                                         \
    {                                                                          \
        dst[0][0] = *(const bf16x8*)(bDir + (k0));                             \
        dst[0][1] = *(const bf16x8*)(bDir + (size_t)16 * K + (k0));            \
        dst[1][0] = *(const bf16x8*)(bDir + (k0) + 32);                        \
        dst[1][1] = *(const bf16x8*)(bDir + (size_t)16 * K + (k0) + 32);       \
    }

#define COMPUTE(breg)                                                          \
    {                                                                          \
        _Pragma("unroll")                                                      \
        for (int s = 0; s < 2; ++s) {                                          \
            const int cs = (s * 4 + quad) ^ (lane16 & 7);                      \
            bf16x8 af[4];                                                      \
            _Pragma("unroll")                                                  \
            for (int mi = 0; mi < 4; ++mi)                                     \
                af[mi] = *(const bf16x8*)(As + (wr * 64 + mi * 16 + lane16) * 64 + cs * 8); \
            _Pragma("unroll")                                                  \
            for (int mi = 0; mi < 4; ++mi)                                     \
                _Pragma("unroll")                                              \
                for (int ni = 0; ni < 2; ++ni)                                 \
                    acc[mi][ni] = __builtin_amdgcn_mfma_f32_16x16x32_bf16(     \
                        af[mi], breg[s][ni], acc[mi][ni], 0, 0, 0);            \
        }                                                                      \
    }

#define TOPSYNC()                                                              \
    asm volatile("s_waitcnt lgkmcnt(0)" ::: "memory");                         \
    __builtin_amdgcn_s_barrier();

#define VMSYNC()                                                               \
    asm volatile("s_waitcnt vmcnt(0)" ::: "memory");                           \
    __builtin_amdgcn_s_barrier();

    // Prologue: B(0); drained (with A-staging) at the first VMSYNC.
    LOADB(bA, 0);

    // 32 K-tiles, unroll-2 (static reg buffers, no copies).
    for (int k0 = 0; k0 < K; k0 += 2 * BK) {
        TOPSYNC();                            // prior ds_reads done; LDS reusable
        STAGEA(k0);
        VMSYNC();                             // As(k0) + all prior B loads drained
        LOADB(bB, k0 + BK);                   // prefetch; drains at NEXT VMSYNC
        COMPUTE(bA);
        TOPSYNC();
        STAGEA(k0 + BK);
        VMSYNC();
        LOADB(bA, (k0 + 2 * BK) & (K - 1));   // wraparound tail: uniform code
        COMPUTE(bB);
    }

#undef STAGEA
#undef LOADB
#undef COMPUTE
#undef TOPSYNC
#undef VMSYNC

    // Epilogue: C/D layout col=lane&15, row=quad*4+reg
    const int rowG = rowBase + wr * 64;
#pragma unroll
    for (int mi = 0; mi < 4; ++mi) {
#pragma unroll
        for (int r = 0; r < 4; ++r) {
            float s = 0.f;
#pragma unroll
            for (int ni = 0; ni < 2; ++ni) {
                int col = colBase + wc * 32 + ni * 16 + lane16;
                float v = acc[mi][ni][r] + b2[col];
                s += tanh_fast(v) * W3[col];
            }
#pragma unroll
            for (int off = 1; off < 16; off <<= 1) s += __shfl_xor(s, off, 64);
            if (lane16 == 0)
                atomicAdd(&rowsum[rowG + mi * 16 + quad * 4 + r], s);
        }
    }
}

// ---------------- Kernel 3: spline gather, 2 points/thread, fused u=3*tanh(rowsum+b3) ----------------
__device__ __forceinline__ float spline_eval(const float* us, float ptx, float pty) {
    float x = (ptx + 1.0f) * 0.5f;
    float px = x * 62.0f, py = pty * 62.0f;
    float fx = floorf(px), fy = floorf(py);
    int posx = min((int)fx + 1, 62);
    int posy = min((int)fy + 1, 62);
    float tx = px - fx, ty = py - fy;
    float bx0 = 0.5f * (1.f - tx) * (1.f - tx);
    float bx1 = -tx * tx + tx + 0.5f;
    float bx2 = 0.5f * tx * tx;
    float by0 = 0.5f * (1.f - ty) * (1.f - ty);
    float by1 = -ty * ty + ty + 0.5f;
    float by2 = 0.5f * ty * ty;
    const float* r0 = &us[(posx - 1) * 64 + (posy - 1)];
    const float* r1 = r0 + 64;
    const float* r2 = r1 + 64;
    float s0 = r0[0] * by0 + r0[1] * by1 + r0[2] * by2;
    float s1 = r1[0] * by0 + r1[1] * by1 + r1[2] * by2;
    float s2 = r2[0] * by0 + r2[1] * by1 + r2[2] * by2;
    return bx0 * s0 + bx1 * s1 + bx2 * s2;
}

__global__ void spline_kernel(const float4* __restrict__ pts,
                              const float* __restrict__ rowsum,
                              const float* __restrict__ b3,
                              float2* __restrict__ out, int npairs) {
    __shared__ float us[4096];
    float bias = b3[0];
    for (int i = threadIdx.x; i < 4096; i += blockDim.x)
        us[i] = 3.0f * tanh_fast(rowsum[i] + bias);
    __syncthreads();
    int stride = gridDim.x * blockDim.x;
    for (int idx = blockIdx.x * blockDim.x + threadIdx.x; idx < npairs; idx += stride) {
        float4 p2 = pts[idx];     // two points
        float2 o;
        o.x = spline_eval(us, p2.x, p2.y);
        o.y = spline_eval(us, p2.z, p2.w);
        out[idx] = o;
    }
}

extern "C" void kernel_launch(void* const* d_in, const int* in_sizes, int n_in,
                              void* d_out, int out_size, void* d_ws, size_t ws_size,
                              hipStream_t stream) {
    const float* points = (const float*)d_in[0];
    const float* W1 = (const float*)d_in[1];
    const float* b1 = (const float*)d_in[2];
    const float* W2 = (const float*)d_in[3];
    const float* b2 = (const float*)d_in[4];
    const float* W3 = (const float*)d_in[5];
    const float* b3 = (const float*)d_in[6];
    float* out = (float*)d_out;

    char* ws = (char*)d_ws;
    unsigned short* hbf = (unsigned short*)ws;                        // 16777216 B
    unsigned short* w2t = (unsigned short*)(ws + 16777216);           //  8388608 B
    float* rowsum = (float*)(ws + 25165824);                          //    16384 B

    prep_all<<<8192 + 1024, 256, 0, stream>>>(W1, b1, W2, hbf, w2t, rowsum);
    gemm_fused<<<1024, 256, 0, stream>>>(hbf, w2t, b2, W3, rowsum);
    spline_kernel<<<1024, 256, 0, stream>>>((const float4*)points, rowsum, b3,
                                            (float2*)out, NPTS / 2);
}

// Round 9
// 169.675 us; speedup vs baseline: 1.2199x; 1.2199x over previous
//
#include <hip/hip_runtime.h>
#include <stdint.h>

#define IN_DIM 4096
#define H_DIM  2048
#define NPTS   2097152

typedef short  bf16x8  __attribute__((ext_vector_type(8)));
typedef float  floatx4 __attribute__((ext_vector_type(4)));

#define AS1 __attribute__((address_space(1)))
#define AS3 __attribute__((address_space(3)))

__device__ __forceinline__ unsigned short f2bf(float f) {
    unsigned u = __float_as_uint(f);
    unsigned r = (u + 0x7FFFu + ((u >> 16) & 1u)) >> 16;   // RNE
    return (unsigned short)r;
}

// Fast tanh: tanh(x) = 1 - 2/(exp(2x)+1) via v_exp_f32 + v_rcp_f32.
__device__ __forceinline__ float tanh_fast(float x) {
    float e = __builtin_amdgcn_exp2f(x * 2.885390081777927f);   // exp(2x)
    return 1.0f - 2.0f * __builtin_amdgcn_rcpf(e + 1.0f);
}

// ---------------- Kernel 1: prep_h + prep_w2t merged; also zeros rowsum ----------------
__global__ void prep_all(const float* __restrict__ W1, const float* __restrict__ b1,
                         const float* __restrict__ W2,
                         unsigned short* __restrict__ hbf, unsigned short* __restrict__ W2T,
                         float* __restrict__ rowsum) {
    __shared__ unsigned short tile[64][66];
    int b = blockIdx.x;
    if (b < 8192) {
        if (b < 16) rowsum[b * 256 + threadIdx.x] = 0.0f;   // 16*256 = 4096
        int idx = (b * 256 + threadIdx.x) * 4;              // covers 8388608
        float4 w = *(const float4*)(W1 + idx);
        float4 bb = *(const float4*)(b1 + (idx & (H_DIM - 1)));
        ushort4 o;
        o.x = f2bf(tanh_fast(w.x + bb.x));
        o.y = f2bf(tanh_fast(w.y + bb.y));
        o.z = f2bf(tanh_fast(w.z + bb.z));
        o.w = f2bf(tanh_fast(w.w + bb.w));
        *(ushort4*)(hbf + idx) = o;
    } else {
        int bb = b - 8192;
        int k0 = (bb >> 5) * 64, n0 = (bb & 31) * 64;
        for (int idx = threadIdx.x; idx < 64 * 64; idx += 256) {
            int r = idx >> 6, c = idx & 63;             // c fast -> coalesced read of W2 row
            tile[c][r] = f2bf(W2[(size_t)(k0 + r) * H_DIM + n0 + c]);
        }
        __syncthreads();
        for (int idx = threadIdx.x; idx < 64 * 64; idx += 256) {
            int r = idx >> 6, c = idx & 63;             // c fast -> coalesced write of W2T row
            W2T[(size_t)(n0 + r) * H_DIM + k0 + c] = tile[r][c];
        }
    }
}

// ---------------- Kernel 2: fused GEMM + tanh + @W3 row-reduce ----------------
// FINAL (reverted to R6 = best measured: gemm 52.4 us, 656 TF).
// Structure: R0 body (128x64 tile, BK=64 single-buffer two-barrier K-loop,
// 24 KB LDS, 4 blocks/CU) + R5 2D XCD-region swizzle (FETCH 69.8->33 MB)
// + R6 tanh_fast epilogue.
// Ledger of refuted alternatives (counter-verified):
//   R1 128x128 tile     -> 512 blocks, 2/CU: 77 us (occupancy-starved)
//   R2 BK=64 dbuf       -> 48 KB LDS, 3/CU: 85 us (occupancy loss > overlap)
//   R3 BK=32 dbuf       -> 4-slot swizzle: 6.29M bank conflicts, 77 us
//   R4 BK=32 dbuf fixed -> 0 conflicts, 4/CU, still 73.7 us (dbuf no help)
//   R7 B->VGPR vmcnt(4) -> NaN (issue order not pinned; rule-#18 class)
//   R8 B->VGPR vmcnt(0) -> 93 us (16-row scatter: 4x vmem requests, 2x B traffic)
// 656 TF == the 2-phase-class ceiling (guide m230/m248: 655-682 TF); within
// ~12% of the LDS-pipe floor (18 LDS ops x ~12 cyc x 512 wave-tiles/CU = 46 us).
// 8-phase 256^2 path infeasible: grid would be 128 blocks (half the GPU idle).
// Staging swizzle (0 conflicts): lane l -> row (l>>3), data chunk (l&7)^(l>>3);
// LDS elem(r,k) @ r*64 + ((k>>3)^(r&7))*8 + (k&7); fragment slot cs=(s*4+quad)^(lane16&7).
#define BK 64
__global__ __launch_bounds__(256, 4) void gemm_fused(
    const unsigned short* __restrict__ A,    // 4096 x 2048 bf16 (h)
    const unsigned short* __restrict__ BT,   // 2048 x 2048 bf16 (W2^T, N x K)
    const float* __restrict__ b2, const float* __restrict__ W3,
    float* __restrict__ rowsum) {
    __shared__ __align__(16) unsigned short As[128 * BK];   // 16 KB
    __shared__ __align__(16) unsigned short Bs[64 * BK];    // 8 KB
    const int K = H_DIM;
    const int t = threadIdx.x;
    const int w = t >> 6, l = t & 63;
    const int lane16 = l & 15, quad = l >> 4;
    const int wr = w >> 1, wc = w & 1;                      // 2x2 waves over 128x64

    // XCD-region swizzle (8 by x 16 bx per XCD)
    const int bid = blockIdx.x;
    const int xcd = bid & 7, idx = bid >> 3;
    const int by = (xcd >> 1) * 8 + (idx >> 4);
    const int bx = (xcd & 1) * 16 + (idx & 15);
    const int rowBase = by * 128;
    const int colBase = bx * 64;

    // per-lane staging offset within an 8-row group (elements)
    const int sRow = l >> 3;                   // 0..7
    const int sChunk = (l & 7) ^ sRow;         // swizzled data chunk
    const size_t laneOff = (size_t)sRow * K + sChunk * 8;

    // wave w stages A rows [w*32, w*32+32) in 4 instrs, B rows [w*16, w*16+16) in 2
    const unsigned short* aBase = A  + (size_t)(rowBase + w * 32) * K + laneOff;
    const unsigned short* bBase = BT + (size_t)(colBase + w * 16) * K + laneOff;

    floatx4 acc[4][2];
    floatx4 zero = {0.f, 0.f, 0.f, 0.f};
#pragma unroll
    for (int i = 0; i < 4; ++i)
#pragma unroll
        for (int j = 0; j < 2; ++j) acc[i][j] = zero;

    for (int k0 = 0; k0 < K; k0 += BK) {
        __syncthreads();          // prior iteration's ds_reads done; LDS reusable
#pragma unroll
        for (int i = 0; i < 4; ++i)
            __builtin_amdgcn_global_load_lds(
                (const AS1 void*)(aBase + (size_t)i * 8 * K + k0),
                (AS3 void*)(As + (w * 32 + i * 8) * 64), 16, 0, 0);
#pragma unroll
        for (int i = 0; i < 2; ++i)
            __builtin_amdgcn_global_load_lds(
                (const AS1 void*)(bBase + (size_t)i * 8 * K + k0),
                (AS3 void*)(Bs + (w * 16 + i * 8) * 64), 16, 0, 0);
        __syncthreads();          // vmcnt(0) drain: tile ready

#pragma unroll
        for (int s = 0; s < 2; ++s) {   // two 16x16x32 k-steps within BK=64
            const int cs = (s * 4 + quad) ^ (lane16 & 7);
            bf16x8 af[4], bfr[2];
#pragma unroll
            for (int mi = 0; mi < 4; ++mi)
                af[mi] = *(const bf16x8*)(As + (wr * 64 + mi * 16 + lane16) * 64 + cs * 8);
#pragma unroll
            for (int ni = 0; ni < 2; ++ni)
                bfr[ni] = *(const bf16x8*)(Bs + (wc * 32 + ni * 16 + lane16) * 64 + cs * 8);
#pragma unroll
            for (int mi = 0; mi < 4; ++mi)
#pragma unroll
                for (int ni = 0; ni < 2; ++ni)
                    acc[mi][ni] = __builtin_amdgcn_mfma_f32_16x16x32_bf16(
                        af[mi], bfr[ni], acc[mi][ni], 0, 0, 0);
        }
    }

    // Epilogue: C/D layout col=lane&15, row=quad*4+reg
    const int rowG = rowBase + wr * 64;
#pragma unroll
    for (int mi = 0; mi < 4; ++mi) {
#pragma unroll
        for (int r = 0; r < 4; ++r) {
            float s = 0.f;
#pragma unroll
            for (int ni = 0; ni < 2; ++ni) {
                int col = colBase + wc * 32 + ni * 16 + lane16;
                float v = acc[mi][ni][r] + b2[col];
                s += tanh_fast(v) * W3[col];
            }
#pragma unroll
            for (int off = 1; off < 16; off <<= 1) s += __shfl_xor(s, off, 64);
            if (lane16 == 0)
                atomicAdd(&rowsum[rowG + mi * 16 + quad * 4 + r], s);
        }
    }
}

// ---------------- Kernel 3: spline gather, 2 points/thread, fused u=3*tanh(rowsum+b3) ----------------
__device__ __forceinline__ float spline_eval(const float* us, float ptx, float pty) {
    float x = (ptx + 1.0f) * 0.5f;
    float px = x * 62.0f, py = pty * 62.0f;
    float fx = floorf(px), fy = floorf(py);
    int posx = min((int)fx + 1, 62);
    int posy = min((int)fy + 1, 62);
    float tx = px - fx, ty = py - fy;
    float bx0 = 0.5f * (1.f - tx) * (1.f - tx);
    float bx1 = -tx * tx + tx + 0.5f;
    float bx2 = 0.5f * tx * tx;
    float by0 = 0.5f * (1.f - ty) * (1.f - ty);
    float by1 = -ty * ty + ty + 0.5f;
    float by2 = 0.5f * ty * ty;
    const float* r0 = &us[(posx - 1) * 64 + (posy - 1)];
    const float* r1 = r0 + 64;
    const float* r2 = r1 + 64;
    float s0 = r0[0] * by0 + r0[1] * by1 + r0[2] * by2;
    float s1 = r1[0] * by0 + r1[1] * by1 + r1[2] * by2;
    float s2 = r2[0] * by0 + r2[1] * by1 + r2[2] * by2;
    return bx0 * s0 + bx1 * s1 + bx2 * s2;
}

__global__ void spline_kernel(const float4* __restrict__ pts,
                              const float* __restrict__ rowsum,
                              const float* __restrict__ b3,
                              float2* __restrict__ out, int npairs) {
    __shared__ float us[4096];
    float bias = b3[0];
    for (int i = threadIdx.x; i < 4096; i += blockDim.x)
        us[i] = 3.0f * tanh_fast(rowsum[i] + bias);
    __syncthreads();
    int stride = gridDim.x * blockDim.x;
    for (int idx = blockIdx.x * blockDim.x + threadIdx.x; idx < npairs; idx += stride) {
        float4 p2 = pts[idx];     // two points
        float2 o;
        o.x = spline_eval(us, p2.x, p2.y);
        o.y = spline_eval(us, p2.z, p2.w);
        out[idx] = o;
    }
}

extern "C" void kernel_launch(void* const* d_in, const int* in_sizes, int n_in,
                              void* d_out, int out_size, void* d_ws, size_t ws_size,
                              hipStream_t stream) {
    const float* points = (const float*)d_in[0];
    const float* W1 = (const float*)d_in[1];
    const float* b1 = (const float*)d_in[2];
    const float* W2 = (const float*)d_in[3];
    const float* b2 = (const float*)d_in[4];
    const float* W3 = (const float*)d_in[5];
    const float* b3 = (const float*)d_in[6];
    float* out = (float*)d_out;

    char* ws = (char*)d_ws;
    unsigned short* hbf = (unsigned short*)ws;                        // 16777216 B
    unsigned short* w2t = (unsigned short*)(ws + 16777216);           //  8388608 B
    float* rowsum = (float*)(ws + 25165824);                          //    16384 B

    prep_all<<<8192 + 1024, 256, 0, stream>>>(W1, b1, W2, hbf, w2t, rowsum);
    gemm_fused<<<1024, 256, 0, stream>>>(hbf, w2t, b2, W3, rowsum);
    spline_kernel<<<1024, 256, 0, stream>>>((const float4*)points, rowsum, b3,
                                            (float2*)out, NPTS / 2);
}